// Round 9
// baseline (1091.171 us; speedup 1.0000x reference)
//
#include <hip/hip_runtime.h>
#include <stdint.h>

#define N_USERS 100000
#define N_NODES 150000
#define D0      128
#define H1      256
#define H2      128
#define NEDGE   4800000
#define BATCH   16384
#define EPSV    1e-5f
#define NBUCK   147          // ceil(150000/1024) coarse buckets (1024 rows each)
#define BCHUNK  4096         // edges per k_bucket block
#define CCHUNK  16384        // edges per k_bcount block

typedef short short8  __attribute__((ext_vector_type(8)));   // 8 bf16 MFMA frag
typedef float floatx4 __attribute__((ext_vector_type(4)));
typedef unsigned int uint2e __attribute__((ext_vector_type(2)));  // clang vectors: valid for
typedef unsigned int uint4e __attribute__((ext_vector_type(4)));  // __builtin_nontemporal_*
typedef unsigned short u16;

__device__ inline float bf2f(u16 u) {
    union { float f; uint32_t i; } x; x.i = ((uint32_t)u) << 16; return x.f;
}
__device__ inline u16 f2bf(float f) {
    union { float f; uint32_t i; } x; x.f = f;
    return (u16)((x.i + 0x7FFFu + ((x.i >> 16) & 1u)) >> 16);  // RNE
}
__device__ inline float itof(uint32_t u) {
    union { float f; uint32_t i; } x; x.i = u; return x.f;
}
__device__ inline uint32_t ftoi(float f) {
    union { float f; uint32_t i; } x; x.f = f; return x.i;
}
__device__ inline uint32_t pack2(float a, float b) {
    return (uint32_t)f2bf(a) | ((uint32_t)f2bf(b) << 16);
}

// ---------------- fused init: canary + zeros ----------------
__global__ __launch_bounds__(256) void k_init(float* __restrict__ out, int out_n,
                                              int* __restrict__ bcount,
                                              float* __restrict__ stats2) {
    int i = blockIdx.x * 256 + threadIdx.x;
    if (i < out_n) out[i] = 2.0f;               // canary
    if (i < NBUCK + 1) bcount[i] = 0;
    if (i < 2 * H2) stats2[i] = 0.f;
}

// ---------------- x (fp32 user||item) -> bf16 xb ----------------
__global__ __launch_bounds__(256) void k_cvt(const float* __restrict__ ue,
                                             const float* __restrict__ ie,
                                             u16* __restrict__ xb) {
    int i = (blockIdx.x * 256 + threadIdx.x) * 4;
    const int NU = N_USERS * D0;
    const int NT = N_NODES * D0;
    if (i >= NT) return;
    const float* src = (i < NU) ? (ue + i) : (ie + (i - NU));
    float4 f = *(const float4*)(const void*)src;
    uint2e w;
    w.x = pack2(f.x, f.y);
    w.y = pack2(f.z, f.w);
    *(uint2e*)(void*)(xb + i) = w;
}

// ---------------- bucket counting: LDS histogram of 147 buckets ----------------
__global__ __launch_bounds__(256) void k_bcount(const int* __restrict__ rows,
                                                int* __restrict__ bcount) {
    __shared__ int h[NBUCK];
    int tid = threadIdx.x;
    for (int i = tid; i < NBUCK; i += 256) h[i] = 0;
    __syncthreads();
    int e0 = blockIdx.x * CCHUNK;
    int nE = NEDGE - e0; if (nE > CCHUNK) nE = CCHUNK;
    for (int i = tid; i < nE; i += 256) atomicAdd(&h[rows[e0 + i] >> 10], 1);
    __syncthreads();
    for (int i = tid; i < NBUCK; i += 256)
        if (h[i] > 0) atomicAdd(&bcount[i], h[i]);
}

// single-block scan of bucket counts -> bucket_base / bucket_cursor; row_ptr[N]=NEDGE
__global__ __launch_bounds__(256) void k_bscan(const int* __restrict__ bcount,
                                               int* __restrict__ bucket_base,
                                               int* __restrict__ bucket_cursor,
                                               int* __restrict__ row_ptr) {
    int tid = threadIdx.x;
    int c = (tid < NBUCK) ? bcount[tid] : 0;
    int lane = tid & 63, wid = tid >> 6;
    int v = c;
    for (int off = 1; off < 64; off <<= 1) {
        int u = __shfl_up(v, off, 64);
        if (lane >= off) v += u;
    }
    __shared__ int wsum[4];
    if (lane == 63) wsum[wid] = v;
    __syncthreads();
    if (tid == 0) {
        int acc = 0;
        for (int w = 0; w < 4; ++w) { int t = wsum[w]; wsum[w] = acc; acc += t; }
    }
    __syncthreads();
    int ex = wsum[wid] + (v - c);
    if (tid < NBUCK) { bucket_base[tid] = ex; bucket_cursor[tid] = ex; }
    if (tid == 0) { bucket_base[NBUCK] = NEDGE; row_ptr[N_NODES] = NEDGE; }
}

// ---------------- pass 1: LDS-staged bucket append (coalesced spans) ----------------
// payload packed: x = (rowlocal<<18) | col, y = val bits
__global__ __launch_bounds__(256) void k_bucket(const int* __restrict__ rows,
                                                const int* __restrict__ cols,
                                                const float* __restrict__ vals,
                                                int* __restrict__ bucket_cursor,
                                                uint2e* __restrict__ etmp) {
    __shared__ uint32_t stx[BCHUNK];       // 16 KB (payload x)
    __shared__ uint32_t sty[BCHUNK];       // 16 KB (payload y)
    __shared__ u16   slotb[BCHUNK];        // 8 KB
    __shared__ int   lcnt[NBUCK + 1];
    __shared__ int   lscan[NBUCK + 1];
    __shared__ int   gstart[NBUCK];
    __shared__ int   wsum[4];
    int tid = threadIdx.x;
    int e0 = blockIdx.x * BCHUNK;
    int nE = NEDGE - e0; if (nE > BCHUNK) nE = BCHUNK;

    for (int i = tid; i <= NBUCK; i += 256) lcnt[i] = 0;
    __syncthreads();
    for (int i = tid; i < nE; i += 256) atomicAdd(&lcnt[rows[e0 + i] >> 10], 1);
    __syncthreads();
    int c = (tid < NBUCK) ? lcnt[tid] : 0;
    if (tid < NBUCK) gstart[tid] = atomicAdd(&bucket_cursor[tid], c);
    // wave-parallel exclusive scan of lcnt -> lscan
    {
        int lane = tid & 63, wid = tid >> 6;
        int v = c;
        for (int off = 1; off < 64; off <<= 1) {
            int u = __shfl_up(v, off, 64);
            if (lane >= off) v += u;
        }
        if (lane == 63) wsum[wid] = v;
        __syncthreads();
        if (tid == 0) {
            int acc = 0;
            for (int w = 0; w < 4; ++w) { int t = wsum[w]; wsum[w] = acc; acc += t; }
        }
        __syncthreads();
        if (tid < NBUCK) lscan[tid] = wsum[wid] + (v - c);
        for (int i = tid; i < NBUCK; i += 256) lcnt[i] = 0;
    }
    __syncthreads();
    for (int i = tid; i < nE; i += 256) {
        int r = rows[e0 + i];
        int b = r >> 10;
        int lidx = atomicAdd(&lcnt[b], 1);
        int slot = lscan[b] + lidx;
        stx[slot] = ((uint32_t)(r & 1023) << 18) |
                    (uint32_t)__builtin_nontemporal_load(&cols[e0 + i]);
        sty[slot] = ftoi(__builtin_nontemporal_load(&vals[e0 + i]));
        slotb[slot] = (u16)b;
    }
    __syncthreads();
    for (int s = tid; s < nE; s += 256) {
        int b = slotb[s];
        uint2e p; p.x = stx[s]; p.y = sty[s];
        __builtin_nontemporal_store(p, &etmp[gstart[b] + (s - lscan[b])]);
    }
}

// ---------------- pass 2: per-bucket row count + LDS scan -> row_ptr; exact placement ----------------
__global__ __launch_bounds__(1024) void k_place2(const int* __restrict__ bucket_base,
                                                 const uint2e* __restrict__ etmp,
                                                 int* __restrict__ row_ptr,
                                                 uint2e* __restrict__ efin) {
    __shared__ int lcnt[1024];
    __shared__ int lcur[1024];
    __shared__ int wsum[16];
    int b = blockIdx.x;
    int tid = threadIdx.x;
    int base = b << 10;
    int bstart = bucket_base[b];
    int bend   = bucket_base[b + 1];
    lcnt[tid] = 0;
    __syncthreads();
    for (int i = bstart + tid; i < bend; i += 1024)
        atomicAdd(&lcnt[etmp[i].x >> 18], 1);
    __syncthreads();
    int c = lcnt[tid];
    int lane = tid & 63, wid = tid >> 6;
    int v = c;
    for (int off = 1; off < 64; off <<= 1) {
        int u = __shfl_up(v, off, 64);
        if (lane >= off) v += u;
    }
    if (lane == 63) wsum[wid] = v;
    __syncthreads();
    if (tid == 0) {
        int acc = 0;
        for (int w = 0; w < 16; ++w) { int t = wsum[w]; wsum[w] = acc; acc += t; }
    }
    __syncthreads();
    int ex = wsum[wid] + (v - c);
    int gpos = bstart + ex;
    if (base + tid < N_NODES) row_ptr[base + tid] = gpos;
    lcur[tid] = gpos;
    __syncthreads();
    for (int i = bstart + tid; i < bend; i += 1024) {
        uint2e p = __builtin_nontemporal_load(&etmp[i]);
        int rl = (int)(p.x >> 18);
        int pos = atomicAdd(&lcur[rl], 1);
        uint2e o; o.x = p.x & 0x3FFFFu; o.y = p.y;
        __builtin_nontemporal_store(o, &efin[pos]);
    }
}

// ---------------- fused weight transposes fp32 -> bf16 (all segments are 32768) ----------------
__global__ __launch_bounds__(256) void k_transpose3(const float* __restrict__ W1,
                                                    const float* __restrict__ W2,
                                                    const float* __restrict__ P1,
                                                    u16* __restrict__ WT1,
                                                    u16* __restrict__ WT2,
                                                    u16* __restrict__ PT1) {
    int gi = blockIdx.x * 256 + threadIdx.x;
    int seg = gi >> 15;           // /32768
    int i = gi & 32767;
    const float* W; u16* WT; int K, N;
    if (seg == 0)      { W = W1; WT = WT1; K = D0;     N = H1; }
    else if (seg == 1) { W = W2; WT = WT2; K = H1;     N = H2; }
    else               { W = P1; WT = PT1; K = 2 * H2; N = H2; }
    int k = i / N, n = i - k * N;
    WT[n * K + k] = f2bf(W[i]);
}

// ---------------- MFMA GEMM, LDS-staged B^T: C = (bnA? relu(A*m+a) : A) @ B + rs*bias ----------------
// optional: per-feature A-side BN (bnm/bna), per-block column stats out (pstat).
__global__ __launch_bounds__(256) void k_gemm(const u16* __restrict__ A, int M, int K,
                                              const u16* __restrict__ BT,
                                              const float* __restrict__ bias,
                                              const float* __restrict__ rowscale,
                                              const float* __restrict__ bnm,
                                              const float* __restrict__ bna,
                                              float2* __restrict__ pstat,
                                              u16* __restrict__ C, int N, int relu) {
    __shared__ u16 lbt[64 * 264];            // 64 x (K+8), K<=256 -> 33.8 KB
    __shared__ float lbnm[256], lbna[256];
    __shared__ float colstat[64][2];
    int tid = threadIdx.x;
    int lane = tid & 63, wid = tid >> 6;
    int m0 = blockIdx.x * 64;
    int n0 = blockIdx.y * 64;
    const int KP = K + 8;
    int cpr = K / 8;
    for (int idx = tid; idx < 64 * cpr; idx += 256) {
        int r = idx / cpr, c = idx - r * cpr;
        *(uint4e*)(void*)(lbt + r * KP + c * 8) =
            *(const uint4e*)(const void*)(BT + (size_t)(n0 + r) * K + c * 8);
    }
    if (bnm) {
        for (int i = tid; i < K; i += 256) { lbnm[i] = bnm[i]; lbna[i] = bna[i]; }
    }
    if (pstat && tid < 128) ((float*)colstat)[tid] = 0.f;
    __syncthreads();
    int rn = lane & 15;
    int kq = (lane >> 4) * 8;
    int mrow = m0 + wid * 16 + rn;
    int mclamp = mrow < M ? mrow : M - 1;
    const u16* aptr = A + (size_t)mclamp * K + kq;
    floatx4 acc0 = {0.f,0.f,0.f,0.f}, acc1 = acc0, acc2 = acc0, acc3 = acc0;
    for (int kt = 0; kt < K; kt += 32) {
        short8 a  = *(const short8*)(const void*)(aptr + kt);
        if (bnm) {   // fused BN+ReLU on A (feature dim = K)
            int kb = kq + kt;
            #pragma unroll
            for (int e = 0; e < 8; ++e) {
                float v = bf2f((u16)a[e]) * lbnm[kb + e] + lbna[kb + e];
                a[e] = (short)f2bf(v < 0.f ? 0.f : v);
            }
        }
        short8 b0 = *(const short8*)(const void*)(lbt + ( 0 + rn) * KP + kq + kt);
        short8 b1 = *(const short8*)(const void*)(lbt + (16 + rn) * KP + kq + kt);
        short8 b2 = *(const short8*)(const void*)(lbt + (32 + rn) * KP + kq + kt);
        short8 b3 = *(const short8*)(const void*)(lbt + (48 + rn) * KP + kq + kt);
        acc0 = __builtin_amdgcn_mfma_f32_16x16x32_bf16(a, b0, acc0, 0, 0, 0);
        acc1 = __builtin_amdgcn_mfma_f32_16x16x32_bf16(a, b1, acc1, 0, 0, 0);
        acc2 = __builtin_amdgcn_mfma_f32_16x16x32_bf16(a, b2, acc2, 0, 0, 0);
        acc3 = __builtin_amdgcn_mfma_f32_16x16x32_bf16(a, b3, acc3, 0, 0, 0);
    }
    int rbase = m0 + wid * 16 + (lane >> 4) * 4;   // C/D: col=lane&15, row=(lane>>4)*4+i
    floatx4 accs[4] = {acc0, acc1, acc2, acc3};
    for (int j = 0; j < 4; ++j) {
        int col = n0 + j * 16 + rn;
        float bs = bias[col];
        float s1 = 0.f, s2 = 0.f;
        for (int i = 0; i < 4; ++i) {
            int row = rbase + i;
            if (row < M) {
                float rs = rowscale ? rowscale[row] : 1.0f;
                float v = accs[j][i] + rs * bs;
                if (relu) v = v < 0.f ? 0.f : v;   // NaN-propagating
                C[(size_t)row * N + col] = f2bf(v);
                s1 += v; s2 += v * v;
            }
        }
        if (pstat) {   // reduce 4 quads (same col) -> lanes 0..15, accumulate in LDS
            s1 += __shfl_down(s1, 32, 64); s1 += __shfl_down(s1, 16, 64);
            s2 += __shfl_down(s2, 32, 64); s2 += __shfl_down(s2, 16, 64);
            if (lane < 16) {
                atomicAdd(&colstat[j * 16 + lane][0], s1);
                atomicAdd(&colstat[j * 16 + lane][1], s2);
            }
        }
    }
    if (pstat) {
        __syncthreads();
        if (tid < 64) {
            float2 o; o.x = colstat[tid][0]; o.y = colstat[tid][1];
            pstat[((size_t)blockIdx.y * gridDim.x + blockIdx.x) * 64 + tid] = o;
        }
    }
}

// ---------------- finalize BN1: reduce pstat -> bnmul/bnadd ----------------
__global__ __launch_bounds__(256) void k_bnfin(const float2* __restrict__ pstat, int GX,
                                               const float* __restrict__ g,
                                               const float* __restrict__ beta,
                                               float* __restrict__ bnmul,
                                               float* __restrict__ bnadd) {
    int f = blockIdx.x;            // one block per feature (H1=256 blocks)
    int by = f >> 6, cl = f & 63;
    int tid = threadIdx.x;
    float s = 0.f, s2 = 0.f;
    for (int bx = tid; bx < GX; bx += 256) {
        float2 p = pstat[((size_t)by * GX + bx) * 64 + cl];
        s += p.x; s2 += p.y;
    }
    for (int off = 32; off > 0; off >>= 1) {
        s += __shfl_down(s, off, 64);
        s2 += __shfl_down(s2, off, 64);
    }
    __shared__ float ws[4][2];
    int lane = tid & 63, wid = tid >> 6;
    if (lane == 0) { ws[wid][0] = s; ws[wid][1] = s2; }
    __syncthreads();
    if (tid == 0) {
        float ts  = ws[0][0] + ws[1][0] + ws[2][0] + ws[3][0];
        float ts2 = ws[0][1] + ws[1][1] + ws[2][1] + ws[3][1];
        float mu = ts * (1.0f / N_NODES);
        float var = ts2 * (1.0f / N_NODES) - mu * mu;
        float sc = rsqrtf(var + EPSV) * g[f];
        bnmul[f] = sc;
        bnadd[f] = beta[f] - mu * sc;
    }
}

// ---------------- aggregation (NF=128): 4 rows/wave, 16 lanes/row, uint4 gathers ----------------
__device__ inline void accum8(float* acc, uint4e r, float v) {
    acc[0] += v * bf2f((u16)(r.x & 0xffffu)); acc[1] += v * bf2f((u16)(r.x >> 16));
    acc[2] += v * bf2f((u16)(r.y & 0xffffu)); acc[3] += v * bf2f((u16)(r.y >> 16));
    acc[4] += v * bf2f((u16)(r.z & 0xffffu)); acc[5] += v * bf2f((u16)(r.z >> 16));
    acc[6] += v * bf2f((u16)(r.w & 0xffffu)); acc[7] += v * bf2f((u16)(r.w >> 16));
}

__global__ __launch_bounds__(256) void k_agg(const u16* __restrict__ t,
                                             const int* __restrict__ row_ptr,
                                             const uint2e* __restrict__ edges,
                                             u16* __restrict__ agg,
                                             float* __restrict__ rowsum) {
    int tid = threadIdx.x;
    int lane = tid & 63;
    int sub = lane >> 4;                 // row slot within wave (0..3)
    int l16 = lane & 15;                 // feature-lane within row
    int row = blockIdx.x * 16 + (tid >> 6) * 4 + sub;   // 150000/16 = 9375 blocks exact
    float acc[8] = {0.f,0.f,0.f,0.f,0.f,0.f,0.f,0.f};
    float sv = 0.f;
    int s = row_ptr[row], e = row_ptr[row + 1];
    const u16* tf = t + l16 * 8;
    int i = s;
    for (; i + 4 <= e; i += 4) {
        uint2e e0 = __builtin_nontemporal_load(&edges[i]);
        uint2e e1 = __builtin_nontemporal_load(&edges[i + 1]);
        uint2e e2 = __builtin_nontemporal_load(&edges[i + 2]);
        uint2e e3 = __builtin_nontemporal_load(&edges[i + 3]);
        uint4e r0 = *(const uint4e*)(const void*)(tf + (size_t)e0.x * 128);
        uint4e r1 = *(const uint4e*)(const void*)(tf + (size_t)e1.x * 128);
        uint4e r2 = *(const uint4e*)(const void*)(tf + (size_t)e2.x * 128);
        uint4e r3 = *(const uint4e*)(const void*)(tf + (size_t)e3.x * 128);
        float v0 = itof(e0.y), v1 = itof(e1.y), v2 = itof(e2.y), v3 = itof(e3.y);
        accum8(acc, r0, v0); accum8(acc, r1, v1);
        accum8(acc, r2, v2); accum8(acc, r3, v3);
        sv += v0 + v1 + v2 + v3;
    }
    for (; i < e; ++i) {
        uint2e e0 = __builtin_nontemporal_load(&edges[i]);
        uint4e r0 = *(const uint4e*)(const void*)(tf + (size_t)e0.x * 128);
        float v0 = itof(e0.y);
        accum8(acc, r0, v0);
        sv += v0;
    }
    uint4e w;
    w.x = pack2(acc[0], acc[1]); w.y = pack2(acc[2], acc[3]);
    w.z = pack2(acc[4], acc[5]); w.w = pack2(acc[6], acc[7]);
    __builtin_nontemporal_store(w, (uint4e*)(void*)(agg + (size_t)row * 128 + l16 * 8));
    if (rowsum != nullptr && l16 == 0) rowsum[row] = sv;
}

// ---------------- BatchNorm stats (layer 2 only) ----------------
__global__ __launch_bounds__(256) void k_bnstats(const u16* __restrict__ agg,
                                                 float* __restrict__ stats, int NF) {
    int tid = threadIdx.x;
    int rpb = 256 / NF;
    int f = tid & (NF - 1);
    int r0 = blockIdx.x * rpb + tid / NF;
    int rs = gridDim.x * rpb;
    float s = 0.f, s2 = 0.f;
    for (int row = r0; row < N_NODES; row += rs) {
        float v = bf2f(agg[(size_t)row * NF + f]);
        s += v; s2 += v * v;
    }
    atomicAdd(&stats[f], s);
    atomicAdd(&stats[NF + f], s2);
}

// ---------------- gather u||v with fused BN2+ReLU -> comb [B,256] bf16 ----------------
__global__ __launch_bounds__(256) void k_gatherBN(const int* __restrict__ ui,
                                                  const int* __restrict__ ii,
                                                  const u16* __restrict__ agg2,
                                                  const float* __restrict__ stats,
                                                  const float* __restrict__ g,
                                                  const float* __restrict__ beta,
                                                  u16* __restrict__ comb) {
    int item = blockIdx.x * 4 + (threadIdx.x >> 6);
    int lane = threadIdx.x & 63;
    if (item >= BATCH) return;
    int node = (lane < 32) ? ui[item] : (N_USERS + ii[item]);
    int fb = (lane & 31) * 4;
    uint2e r = *(const uint2e*)(const void*)(agg2 + (size_t)node * H2 + fb);
    float vv[4] = { bf2f((u16)(r.x & 0xffffu)), bf2f((u16)(r.x >> 16)),
                    bf2f((u16)(r.y & 0xffffu)), bf2f((u16)(r.y >> 16)) };
    u16 o[4];
    for (int j = 0; j < 4; ++j) {
        int f = fb + j;
        float mu = stats[f] * (1.0f / N_NODES);
        float var = stats[H2 + f] * (1.0f / N_NODES) - mu * mu;
        float sc = rsqrtf(var + EPSV) * g[f];
        float v = (vv[j] - mu) * sc + beta[f];
        o[j] = f2bf(v < 0.f ? 0.f : v);
    }
    uint2e w;
    w.x = (uint32_t)o[0] | ((uint32_t)o[1] << 16);
    w.y = (uint32_t)o[2] | ((uint32_t)o[3] << 16);
    *(uint2e*)(void*)(comb + (size_t)item * (2 * H2) + lane * 4) = w;
}

// ---------------- final dot ----------------
__global__ __launch_bounds__(256) void k_final(const u16* __restrict__ h,
                                               const float* __restrict__ P2,
                                               const float* __restrict__ pb2,
                                               float* __restrict__ out) {
    int item = blockIdx.x * 4 + (threadIdx.x >> 6);
    int lane = threadIdx.x & 63;
    if (item >= BATCH) return;
    float a = bf2f(h[(size_t)item * H2 + lane])      * P2[lane]
            + bf2f(h[(size_t)item * H2 + 64 + lane]) * P2[64 + lane];
    for (int off = 32; off > 0; off >>= 1) a += __shfl_down(a, off, 64);
    if (lane == 0) out[item] = a + pb2[0];
}

extern "C" void kernel_launch(void* const* d_in, const int* in_sizes, int n_in,
                              void* d_out, int out_size, void* d_ws, size_t ws_size,
                              hipStream_t stream) {
    (void)in_sizes; (void)n_in; (void)ws_size;
    const int* user_indices = (const int*)d_in[0];
    const int* item_indices = (const int*)d_in[1];
    const int* edge_rows    = (const int*)d_in[2];
    const int* edge_cols    = (const int*)d_in[3];
    const float* edge_vals = (const float*)d_in[4];
    const float* user_emb  = (const float*)d_in[5];
    const float* item_emb  = (const float*)d_in[6];
    const float* W1    = (const float*)d_in[7];
    const float* b1    = (const float*)d_in[8];
    const float* g1    = (const float*)d_in[9];
    const float* beta1 = (const float*)d_in[10];
    const float* W2    = (const float*)d_in[11];
    const float* b2    = (const float*)d_in[12];
    const float* g2    = (const float*)d_in[13];
    const float* beta2 = (const float*)d_in[14];
    const float* P1    = (const float*)d_in[15];
    const float* pb1   = (const float*)d_in[16];
    const float* P2    = (const float*)d_in[17];
    const float* pb2   = (const float*)d_in[18];
    float* out = (float*)d_out;

    const int GX1 = (N_NODES + 63) / 64;   // 2344 row-blocks for gemm1

    // workspace layout (~200 MB)
    char* ws = (char*)d_ws;
    size_t off = 0;
    auto alloc = [&](size_t bytes) -> char* {
        char* p = ws + off;
        off = (off + bytes + 255) & ~(size_t)255;
        return p;
    };
    int*   row_ptr  = (int*)alloc(sizeof(int) * (N_NODES + 1));
    int*   bcount   = (int*)alloc(sizeof(int) * (NBUCK + 1));
    int*   bbase    = (int*)alloc(sizeof(int) * (NBUCK + 1));
    int*   bcursor  = (int*)alloc(sizeof(int) * (NBUCK + 1));
    float* rowsum   = (float*)alloc(sizeof(float) * N_NODES);
    float* stats2   = (float*)alloc(sizeof(float) * 2 * H2);
    float* bnm1     = (float*)alloc(sizeof(float) * H1);
    float* bna1     = (float*)alloc(sizeof(float) * H1);
    float2* pstat   = (float2*)alloc(sizeof(float2) * 4 * (size_t)GX1 * 64);  // 4.8 MB
    u16* WT1 = (u16*)alloc(2 * D0 * H1);
    u16* WT2 = (u16*)alloc(2 * H1 * H2);
    u16* PT1 = (u16*)alloc(2 * 2 * H2 * H2);
    uint2e* efin = (uint2e*)alloc(8 * (size_t)NEDGE);   // final CSR edges (38.4 MB)
    // R1 (76.8 MB): [lo] xb -> t2 ; [hi] aggx -> agg2
    u16* R1   = (u16*)alloc(2 * (size_t)N_NODES * H1);
    u16* xb   = R1;
    u16* aggx = R1 + (size_t)N_NODES * D0;
    u16* t2   = R1;                                      // reuses xb (dead after agg1)
    u16* agg2 = R1 + (size_t)N_NODES * D0;               // reuses aggx (dead after gemm1)
    // R2 (76.8 MB): etmp (sort scratch) -> agg1 (full) -> comb+hbuf
    u16* R2   = (u16*)alloc(2 * (size_t)N_NODES * H1);
    uint2e* etmp = (uint2e*)R2;                          // dead after k_place2
    u16* agg1 = R2;                                      // full 76.8 MB, dead after gemm2
    u16* comb = R2;
    u16* hbuf = R2 + (size_t)BATCH * 2 * H2;

    // fused init (canary 2.0 + zero bcount/stats2)
    k_init<<<(out_size + 255) / 256, 256, 0, stream>>>(out, out_size, bcount, stats2);

    // x -> bf16
    k_cvt<<<(N_NODES * D0 / 4 + 255) / 256, 256, 0, stream>>>(user_emb, item_emb, xb);

    // CSR build: bucket-count -> scan(147) -> bucket stage -> place (+row_ptr)
    k_bcount<<<(NEDGE + CCHUNK - 1) / CCHUNK, 256, 0, stream>>>(edge_rows, bcount);
    k_bscan<<<1, 256, 0, stream>>>(bcount, bbase, bcursor, row_ptr);
    k_bucket<<<(NEDGE + BCHUNK - 1) / BCHUNK, 256, 0, stream>>>(
        edge_rows, edge_cols, edge_vals, bcursor, etmp);
    k_place2<<<NBUCK, 1024, 0, stream>>>(bbase, etmp, row_ptr, efin);

    // fused weight transposes fp32 -> bf16 (B^T layout)
    k_transpose3<<<(3 * 32768) / 256, 256, 0, stream>>>(W1, W2, P1, WT1, WT2, PT1);

    // layer 1: aggx = agg(xb); agg1 = aggx@W1 + s_r*b1 (+ fused col stats -> pstat)
    k_agg<<<N_NODES / 16, 256, 0, stream>>>(xb, row_ptr, efin, aggx, rowsum);
    k_gemm<<<dim3(GX1, H1 / 64), 256, 0, stream>>>(
        aggx, N_NODES, D0, WT1, b1, rowsum, nullptr, nullptr, pstat, agg1, H1, 0);
    k_bnfin<<<H1, 256, 0, stream>>>(pstat, GX1, g1, beta1, bnm1, bna1);

    // layer 2: t2 = relu(BN1(agg1))@W2 + b2 (BN fused in A-load); agg2 = agg(t2)
    k_gemm<<<dim3(GX1, H2 / 64), 256, 0, stream>>>(
        agg1, N_NODES, H1, WT2, b2, nullptr, bnm1, bna1, nullptr, t2, H2, 0);
    k_agg<<<N_NODES / 16, 256, 0, stream>>>(t2, row_ptr, efin, agg2, nullptr);
    k_bnstats<<<512, 256, 0, stream>>>(agg2, stats2, H2);

    // head: gather with fused BN2+ReLU, MLP, dot
    k_gatherBN<<<BATCH / 4, 256, 0, stream>>>(user_indices, item_indices, agg2,
                                              stats2, g2, beta2, comb);
    k_gemm<<<dim3(BATCH / 64, H2 / 64), 256, 0, stream>>>(
        comb, BATCH, 2 * H2, PT1, pb1, nullptr, nullptr, nullptr, nullptr, hbuf, H2, 1);
    k_final<<<BATCH / 4, 256, 0, stream>>>(hbuf, P2, pb2, out);
}